// Round 17
// baseline (127.445 us; speedup 1.0000x reference)
//
#include <hip/hip_runtime.h>
#include <stdint.h>

// Problem geometry
#define DD    64          // slices
#define HH    512         // rows
#define WWID  512         // cols
#define WPR   8           // u64 words per row (512 bits)
#define NSUB  48          // 24 full iterations x 2 sub-iterations
#define BANDS 4           // row-bands per slice
#define BH    128         // output rows per band
#define HALO  52          // 48 (thinning) + 4 (closing)
#define MAXR  (BH + 2*HALO)   // 232 live rows max
#define ARR   (MAXR + 4)      // +2 guard rows each side = 236
#define PITCH 12              // 96B stride: bank-group shift 6/row
#define WOFF  2               // word j at LDS idx j+WOFF; pads 0,11; guards 1,10
#define NTHR  1024            // 4 threads/row (2 u64 words each), 16 waves

typedef unsigned long long u64;

// ---------------- kernel 1: threshold + bit-pack via ballot ----------------
__global__ void pack_kernel(const float* __restrict__ in, u64* __restrict__ bits) {
    long gid  = (long)blockIdx.x * blockDim.x + threadIdx.x;
    long wv   = gid >> 6;
    int  lane = (int)(gid & 63);
    long base = wv * 256;
    #pragma unroll
    for (int k = 0; k < 4; ++k) {
        float v = in[base + (long)k * 64 + lane];
        u64 m = __ballot(v > 0.5f);
        if (lane == 0) bits[wv * 4 + k] = m;
    }
}

// ---- 64-bit funnel shifts by 1/2 via v_alignbit_b32 (2 ops each) ----
__device__ __forceinline__ u64 fshl(u64 c, u64 pl, int nbit) {   // (c<<n)|(pl>>(64-n))
    uint2 C = __builtin_bit_cast(uint2, c);
    uint2 P = __builtin_bit_cast(uint2, pl);
    uint2 R;
    R.x = __builtin_amdgcn_alignbit(C.x, P.y, 32 - nbit);
    R.y = __builtin_amdgcn_alignbit(C.y, C.x, 32 - nbit);
    return __builtin_bit_cast(u64, R);
}
__device__ __forceinline__ u64 fshr(u64 c, u64 pr, int nbit) {   // (c>>n)|(pr<<(64-n))
    uint2 C = __builtin_bit_cast(uint2, c);
    uint2 P = __builtin_bit_cast(uint2, pr);
    uint2 R;
    R.x = __builtin_amdgcn_alignbit(C.y, C.x, nbit);
    R.y = __builtin_amdgcn_alignbit(P.x, C.y, nbit);
    return __builtin_bit_cast(u64, R);
}

// Zhang-Suen delete test for one 64-pixel word, bit-sliced. sub is a literal.
__device__ __forceinline__ u64 zs_word(u64 c, u64 N, u64 NE, u64 E, u64 SE,
                                       u64 S, u64 SW, u64 Wn, u64 NW, int sub) {
    u64 t0 = ~N  & NE;
    u64 t1 = ~NE & E;
    u64 t2 = ~E  & SE;
    u64 t3 = ~SE & S;
    u64 t4 = ~S  & SW;
    u64 t5 = ~SW & Wn;
    u64 t6 = ~Wn & NW;
    u64 t7 = ~NW & N;
    u64 o01 = t0 ^ t1, w01 = t0 & t1;
    u64 o23 = t2 ^ t3, w23 = t2 & t3;
    u64 o45 = t4 ^ t5, w45 = t4 & t5;
    u64 o67 = t6 ^ t7, w67 = t6 & t7;
    u64 oA = o01 ^ o23, wA = w01 | w23 | (o01 & o23);
    u64 oB = o45 ^ o67, wB = w45 | w67 | (o45 & o67);
    u64 A1 = (oA ^ oB) & ~(wA | wB | (oA & oB));
    u64 sa, ca; { u64 tt = N ^ NE; sa = tt ^ E;  ca = (N & NE) | (tt & E);  }
    u64 sb, cb; { u64 tt = SE ^ S; sb = tt ^ SW; cb = (SE & S) | (tt & SW); }
    u64 sc = Wn ^ NW, cc = Wn & NW;
    u64 S0, cd; { u64 tt = sa ^ sb; S0 = tt ^ sc;  cd = (sa & sb) | (tt & sc); }
    u64 t2s, ce; { u64 tt = ca ^ cb; t2s = tt ^ cc; ce = (ca & cb) | (tt & cc); }
    u64 S1 = cd ^ t2s, cf = cd & t2s;
    u64 S2 = ce ^ cf,  S3 = ce & cf;
    u64 cB = (S1 | S2 | S3) & ~((S2 & S1 & S0) | S3);
    u64 c3, c4;
    if (sub == 0) { c3 = ~(N & E & S);  c4 = ~(E & S & Wn); }
    else          { c3 = ~(N & E & Wn); c4 = ~(N & S & Wn); }
    return c & ~(cB & A1 & c3 & c4);
}

// Closing phase: this thread owns words wb (A) and wb+1 (B).
#define CLOSE_PHASE(SRC, DST, ISDIL, SETREG) do {                                       \
    if (act) {                                                                          \
        u64 s_[5][6];                                                                   \
        _Pragma("unroll") for (int rr = 0; rr < 5; ++rr) {                              \
            ulonglong2 v0 = *reinterpret_cast<const ulonglong2*>(&SRC[ar-2+rr][wb-2]);  \
            ulonglong2 v1 = *reinterpret_cast<const ulonglong2*>(&SRC[ar-2+rr][wb]);    \
            ulonglong2 v2 = *reinterpret_cast<const ulonglong2*>(&SRC[ar-2+rr][wb+2]);  \
            s_[rr][0]=v0.x; s_[rr][1]=v0.y; s_[rr][2]=v1.x;                             \
            s_[rr][3]=v1.y; s_[rr][4]=v2.x; s_[rr][5]=v2.y;                             \
        }                                                                               \
        u64 rA, rB;                                                                     \
        _Pragma("unroll") for (int jj = 0; jj < 2; ++jj) {                              \
            u64 c  = s_[2][jj+2], pl = s_[2][jj+1], pr = s_[2][jj+3];                   \
            u64 l1 = fshl(c, pl, 1), l2 = fshl(c, pl, 2);                               \
            u64 r1 = fshr(c, pr, 1), r2 = fshr(c, pr, 2);                               \
            u64 u_ = s_[1][jj+2], ul = fshl(u_, s_[1][jj+1], 1), ur = fshr(u_, s_[1][jj+3], 1);\
            u64 d_ = s_[3][jj+2], dl = fshl(d_, s_[3][jj+1], 1), dr = fshr(d_, s_[3][jj+3], 1);\
            u64 u2 = s_[0][jj+2], d2 = s_[4][jj+2];                                     \
            u64 r_ = ISDIL ? (c|l1|l2|r1|r2|u_|ul|ur|d_|dl|dr|u2|d2)                    \
                           : (c&l1&l2&r1&r2&u_&ul&ur&d_&dl&dr&u2&d2);                   \
            if (jj == 0) rA = r_; else rB = r_;                                         \
        }                                                                               \
        ulonglong2 st; st.x = rA; st.y = rB;                                            \
        *reinterpret_cast<ulonglong2*>(&DST[ar][wb]) = st;                              \
        if (SETREG) { myw0 = rA; myw1 = rB; }                                           \
    }                                                                                   \
    __syncthreads();                                                                    \
} while (0)

// Thinning sub-iteration: center pair in registers; c-row side words via shfl;
// u/d rows from LDS (compiler-scheduled — no asm fences, R16 lesson).
#define THIN_SUB(SRC, DST, SUB, LO, HI) do {                                            \
    if (act && lr >= (LO) && lr < (HI)) {                                               \
        ulonglong2 ub = *reinterpret_cast<const ulonglong2*>(&SRC[ar-1][wb]);           \
        u64 u_l = SRC[ar-1][wb-1];                                                      \
        u64 u_r = SRC[ar-1][wb+2];                                                      \
        ulonglong2 db = *reinterpret_cast<const ulonglong2*>(&SRC[ar+1][wb]);           \
        u64 d_l = SRC[ar+1][wb-1];                                                      \
        u64 d_r = SRC[ar+1][wb+2];                                                      \
        u64 sl  = __shfl_up((unsigned long long)myw1, 1, 64);                           \
        u64 sr  = __shfl_down((unsigned long long)myw0, 1, 64);                         \
        u64 c_l = (q > 0) ? sl : 0ull;                                                  \
        u64 c_r = (q < 3) ? sr : 0ull;                                                  \
        u64 rA, rB;                                                                     \
        { u64 c = myw0, pl = c_l, pr = myw1;                                            \
          u64 N  = ub.x, S = db.x;                                                      \
          u64 E  = fshr(c, pr, 1),      Wn = fshl(c, pl, 1);                            \
          u64 NE = fshr(ub.x, ub.y, 1), NW = fshl(ub.x, u_l, 1);                        \
          u64 SE = fshr(db.x, db.y, 1), SW = fshl(db.x, d_l, 1);                        \
          rA = zs_word(c, N, NE, E, SE, S, SW, Wn, NW, SUB); }                          \
        { u64 c = myw1, pl = myw0, pr = c_r;                                            \
          u64 N  = ub.y, S = db.y;                                                      \
          u64 E  = fshr(c, pr, 1),      Wn = fshl(c, pl, 1);                            \
          u64 NE = fshr(ub.y, u_r, 1),  NW = fshl(ub.y, ub.x, 1);                       \
          u64 SE = fshr(db.y, d_r, 1),  SW = fshl(db.y, db.x, 1);                       \
          rB = zs_word(c, N, NE, E, SE, S, SW, Wn, NW, SUB); }                          \
        ulonglong2 st; st.x = rA; st.y = rB;                                            \
        *reinterpret_cast<ulonglong2*>(&DST[ar][wb]) = st;                              \
        myw0 = rA; myw1 = rB;                                                           \
    }                                                                                   \
    __syncthreads();                                                                    \
} while (0)

// ---------------- kernel 2: closing + 48x thinning in LDS ----------------
__global__ __launch_bounds__(NTHR, 8)
void thin_kernel(const u64* __restrict__ bits, int* __restrict__ out) {
    __shared__ u64 bufA[ARR][PITCH];
    __shared__ u64 bufB[ARR][PITCH];

    const int blk  = blockIdx.x;
    const int z    = blk >> 2;       // slice
    const int band = blk & 3;
    const int r0   = band * BH;      // first output row
    const int la   = (r0 - HALO > 0) ? (r0 - HALO) : 0;
    const int lb   = (r0 + BH + HALO < HH) ? (r0 + BH + HALO) : HH;
    const int nrows = lb - la;       // live rows (<= 232)
    const int ob0  = r0 - la;        // local output start (0 or 52)

    const int t  = threadIdx.x;
    const int lr = t >> 2;           // row handled by this thread (0..255)
    const int q  = t & 3;            // word-pair index 0..3
    const int wb = 2 * q + WOFF;     // LDS idx of first owned word
    const int ar = lr + 2;           // array row (2 guard rows at top)
    const bool act = (lr < nrows);

    u64 myw0 = 0, myw1 = 0;          // register-resident center words

    // ---- zero both buffers (guards/pads must be 0 in both) ----
    {
        u64* fa = &bufA[0][0];
        u64* fb = &bufB[0][0];
        for (int i = t; i < ARR * PITCH; i += NTHR) { fa[i] = 0; fb[i] = 0; }
    }
    __syncthreads();

    // ---- load packed raw mask into bufA live area ----
    if (act) {
        const u64* src = bits + ((long)(z * HH + la + lr)) * WPR + 2 * q;
        ulonglong2 v = *reinterpret_cast<const ulonglong2*>(src);
        *reinterpret_cast<ulonglong2*>(&bufA[ar][wb]) = v;
    }
    __syncthreads();

    // ---- closing: dilation (A->B) then erosion (B->A, seeds registers) ----
    CLOSE_PHASE(bufA, bufB, 1, 0);
    CLOSE_PHASE(bufB, bufA, 0, 1);

    // ---- 48 Zhang-Suen sub-iterations, shrinking active range ----
    #pragma unroll 1
    for (int it2 = 0; it2 < NSUB / 2; ++it2) {
        {
            int hw = NSUB - (2 * it2 + 1);
            int lo = ob0 - hw;       if (lo < 0) lo = 0;
            int hi = ob0 + BH + hw;  if (hi > nrows) hi = nrows;
            THIN_SUB(bufA, bufB, 0, lo, hi);
        }
        {
            int hw = NSUB - (2 * it2 + 2);
            int lo = ob0 - hw;       if (lo < 0) lo = 0;
            int hi = ob0 + BH + hw;  if (hi > nrows) hi = nrows;
            THIN_SUB(bufB, bufA, 1, lo, hi);
        }
    }
    // final state is in bufA

    // ---- expand: 1024 threads = 128 rows x 8 words; each thread reads its
    // u64 ONCE and emits 16 unrolled int4 stores (256B contiguous).
    {
        const long slice_base = (long)z * HH * WWID;
        int wsel = t & 7;            // word 0..7
        int rr   = t >> 3;           // output row 0..127
        int gr   = r0 + rr;
        int arr  = (gr - la) + 2;
        u64 w = bufA[arr][WOFF + wsel];
        int* po = out + slice_base + (long)gr * WWID + wsel * 64;
        #pragma unroll
        for (int j = 0; j < 16; ++j) {
            int4 f;
            f.x = (int)((w >> (4 * j + 0)) & 1ull);
            f.y = (int)((w >> (4 * j + 1)) & 1ull);
            f.z = (int)((w >> (4 * j + 2)) & 1ull);
            f.w = (int)((w >> (4 * j + 3)) & 1ull);
            reinterpret_cast<int4*>(po)[j] = f;
        }
    }
}

extern "C" void kernel_launch(void* const* d_in, const int* in_sizes, int n_in,
                              void* d_out, int out_size, void* d_ws, size_t ws_size,
                              hipStream_t stream) {
    const float* in   = (const float*)d_in[0];
    int*         out  = (int*)d_out;
    u64*         bits = (u64*)d_ws;   // 2 MiB scratch

    pack_kernel<<<16384, 256, 0, stream>>>(in, bits);
    thin_kernel<<<DD * BANDS, NTHR, 0, stream>>>(bits, out);
}

// Round 18
// 111.850 us; speedup vs baseline: 1.1394x; 1.1394x over previous
//
#include <hip/hip_runtime.h>
#include <stdint.h>

// Problem geometry
#define DD    64          // slices
#define HH    512         // rows
#define WWID  512         // cols
#define WPR   8           // u64 words per row (512 bits)
#define NSUB  48          // 24 full iterations x 2 sub-iterations
#define BANDS 4           // row-bands per slice
#define BH    128         // output rows per band
#define HALO  52          // 48 (thinning) + 4 (closing)
#define MAXR  (BH + 2*HALO)   // 232 live rows max
#define ARR   (MAXR + 4)      // +2 guard rows each side = 236
#define PITCH 12              // 96B stride: bank-group shift 6/row
#define WOFF  2               // word j at LDS idx j+WOFF; pads 0,11; guards 1,10
#define NTHR  1024            // 4 threads/row (2 u64 words each), 16 waves

typedef unsigned long long u64;

// ---------------- kernel 1: threshold + bit-pack via ballot ----------------
__global__ void pack_kernel(const float* __restrict__ in, u64* __restrict__ bits) {
    long gid  = (long)blockIdx.x * blockDim.x + threadIdx.x;
    long wv   = gid >> 6;
    int  lane = (int)(gid & 63);
    long base = wv * 256;
    #pragma unroll
    for (int k = 0; k < 4; ++k) {
        float v = in[base + (long)k * 64 + lane];
        u64 m = __ballot(v > 0.5f);
        if (lane == 0) bits[wv * 4 + k] = m;
    }
}

// ---- 64-bit funnel shifts by 1/2 via v_alignbit_b32 (2 ops each) ----
__device__ __forceinline__ u64 fshl(u64 c, u64 pl, int nbit) {   // (c<<n)|(pl>>(64-n))
    uint2 C = __builtin_bit_cast(uint2, c);
    uint2 P = __builtin_bit_cast(uint2, pl);
    uint2 R;
    R.x = __builtin_amdgcn_alignbit(C.x, P.y, 32 - nbit);
    R.y = __builtin_amdgcn_alignbit(C.y, C.x, 32 - nbit);
    return __builtin_bit_cast(u64, R);
}
__device__ __forceinline__ u64 fshr(u64 c, u64 pr, int nbit) {   // (c>>n)|(pr<<(64-n))
    uint2 C = __builtin_bit_cast(uint2, c);
    uint2 P = __builtin_bit_cast(uint2, pr);
    uint2 R;
    R.x = __builtin_amdgcn_alignbit(C.y, C.x, nbit);
    R.y = __builtin_amdgcn_alignbit(P.x, C.y, nbit);
    return __builtin_bit_cast(u64, R);
}

// ---- lane+-1 exchange via DPP (VALU pipe, not LDS/bpermute) ----
// row_shr:1 (0x111): dst[lane]=src[lane-1] within 16-lane rows (shuffle-up).
// row_shl:1 (0x101): dst[lane]=src[lane+1] (shuffle-down). Cross-image-row
// pulls only occur at q==0 / q==3, which are masked to the zero-guard anyway.
__device__ __forceinline__ u64 dpp_up1(u64 v) {
    uint2 V = __builtin_bit_cast(uint2, v);
    uint2 R;
    R.x = __builtin_amdgcn_update_dpp(0, (int)V.x, 0x111, 0xF, 0xF, true);
    R.y = __builtin_amdgcn_update_dpp(0, (int)V.y, 0x111, 0xF, 0xF, true);
    return __builtin_bit_cast(u64, R);
}
__device__ __forceinline__ u64 dpp_dn1(u64 v) {
    uint2 V = __builtin_bit_cast(uint2, v);
    uint2 R;
    R.x = __builtin_amdgcn_update_dpp(0, (int)V.x, 0x101, 0xF, 0xF, true);
    R.y = __builtin_amdgcn_update_dpp(0, (int)V.y, 0x101, 0xF, 0xF, true);
    return __builtin_bit_cast(u64, R);
}

// Zhang-Suen delete test for one 64-pixel word, bit-sliced. sub is a literal.
__device__ __forceinline__ u64 zs_word(u64 c, u64 N, u64 NE, u64 E, u64 SE,
                                       u64 S, u64 SW, u64 Wn, u64 NW, int sub) {
    u64 t0 = ~N  & NE;
    u64 t1 = ~NE & E;
    u64 t2 = ~E  & SE;
    u64 t3 = ~SE & S;
    u64 t4 = ~S  & SW;
    u64 t5 = ~SW & Wn;
    u64 t6 = ~Wn & NW;
    u64 t7 = ~NW & N;
    u64 o01 = t0 ^ t1, w01 = t0 & t1;
    u64 o23 = t2 ^ t3, w23 = t2 & t3;
    u64 o45 = t4 ^ t5, w45 = t4 & t5;
    u64 o67 = t6 ^ t7, w67 = t6 & t7;
    u64 oA = o01 ^ o23, wA = w01 | w23 | (o01 & o23);
    u64 oB = o45 ^ o67, wB = w45 | w67 | (o45 & o67);
    u64 A1 = (oA ^ oB) & ~(wA | wB | (oA & oB));
    u64 sa, ca; { u64 tt = N ^ NE; sa = tt ^ E;  ca = (N & NE) | (tt & E);  }
    u64 sb, cb; { u64 tt = SE ^ S; sb = tt ^ SW; cb = (SE & S) | (tt & SW); }
    u64 sc = Wn ^ NW, cc = Wn & NW;
    u64 S0, cd; { u64 tt = sa ^ sb; S0 = tt ^ sc;  cd = (sa & sb) | (tt & sc); }
    u64 t2s, ce; { u64 tt = ca ^ cb; t2s = tt ^ cc; ce = (ca & cb) | (tt & cc); }
    u64 S1 = cd ^ t2s, cf = cd & t2s;
    u64 S2 = ce ^ cf,  S3 = ce & cf;
    u64 cB = (S1 | S2 | S3) & ~((S2 & S1 & S0) | S3);
    u64 c3, c4;
    if (sub == 0) { c3 = ~(N & E & S);  c4 = ~(E & S & Wn); }
    else          { c3 = ~(N & E & Wn); c4 = ~(N & S & Wn); }
    return c & ~(cB & A1 & c3 & c4);
}

// Closing phase: this thread owns words wb (A) and wb+1 (B).
#define CLOSE_PHASE(SRC, DST, ISDIL, SETREG) do {                                       \
    if (act) {                                                                          \
        u64 s_[5][6];                                                                   \
        _Pragma("unroll") for (int rr = 0; rr < 5; ++rr) {                              \
            ulonglong2 v0 = *reinterpret_cast<const ulonglong2*>(&SRC[ar-2+rr][wb-2]);  \
            ulonglong2 v1 = *reinterpret_cast<const ulonglong2*>(&SRC[ar-2+rr][wb]);    \
            ulonglong2 v2 = *reinterpret_cast<const ulonglong2*>(&SRC[ar-2+rr][wb+2]);  \
            s_[rr][0]=v0.x; s_[rr][1]=v0.y; s_[rr][2]=v1.x;                             \
            s_[rr][3]=v1.y; s_[rr][4]=v2.x; s_[rr][5]=v2.y;                             \
        }                                                                               \
        u64 rA, rB;                                                                     \
        _Pragma("unroll") for (int jj = 0; jj < 2; ++jj) {                              \
            u64 c  = s_[2][jj+2], pl = s_[2][jj+1], pr = s_[2][jj+3];                   \
            u64 l1 = fshl(c, pl, 1), l2 = fshl(c, pl, 2);                               \
            u64 r1 = fshr(c, pr, 1), r2 = fshr(c, pr, 2);                               \
            u64 u_ = s_[1][jj+2], ul = fshl(u_, s_[1][jj+1], 1), ur = fshr(u_, s_[1][jj+3], 1);\
            u64 d_ = s_[3][jj+2], dl = fshl(d_, s_[3][jj+1], 1), dr = fshr(d_, s_[3][jj+3], 1);\
            u64 u2 = s_[0][jj+2], d2 = s_[4][jj+2];                                     \
            u64 r_ = ISDIL ? (c|l1|l2|r1|r2|u_|ul|ur|d_|dl|dr|u2|d2)                    \
                           : (c&l1&l2&r1&r2&u_&ul&ur&d_&dl&dr&u2&d2);                   \
            if (jj == 0) rA = r_; else rB = r_;                                         \
        }                                                                               \
        ulonglong2 st; st.x = rA; st.y = rB;                                            \
        *reinterpret_cast<ulonglong2*>(&DST[ar][wb]) = st;                              \
        if (SETREG) { myw0 = rA; myw1 = rB; }                                           \
    }                                                                                   \
    __syncthreads();                                                                    \
} while (0)

// Thinning sub-iteration: center pair in registers; c-row side words via DPP;
// u/d rows from LDS (compiler-scheduled — no asm fences).
#define THIN_SUB(SRC, DST, SUB, LO, HI) do {                                            \
    if (act && lr >= (LO) && lr < (HI)) {                                               \
        ulonglong2 ub = *reinterpret_cast<const ulonglong2*>(&SRC[ar-1][wb]);           \
        u64 u_l = SRC[ar-1][wb-1];                                                      \
        u64 u_r = SRC[ar-1][wb+2];                                                      \
        ulonglong2 db = *reinterpret_cast<const ulonglong2*>(&SRC[ar+1][wb]);           \
        u64 d_l = SRC[ar+1][wb-1];                                                      \
        u64 d_r = SRC[ar+1][wb+2];                                                      \
        u64 sl  = dpp_up1(myw1);                                                        \
        u64 sr  = dpp_dn1(myw0);                                                        \
        u64 c_l = (q > 0) ? sl : 0ull;                                                  \
        u64 c_r = (q < 3) ? sr : 0ull;                                                  \
        u64 rA, rB;                                                                     \
        { u64 c = myw0, pl = c_l, pr = myw1;                                            \
          u64 N  = ub.x, S = db.x;                                                      \
          u64 E  = fshr(c, pr, 1),      Wn = fshl(c, pl, 1);                            \
          u64 NE = fshr(ub.x, ub.y, 1), NW = fshl(ub.x, u_l, 1);                        \
          u64 SE = fshr(db.x, db.y, 1), SW = fshl(db.x, d_l, 1);                        \
          rA = zs_word(c, N, NE, E, SE, S, SW, Wn, NW, SUB); }                          \
        { u64 c = myw1, pl = myw0, pr = c_r;                                            \
          u64 N  = ub.y, S = db.y;                                                      \
          u64 E  = fshr(c, pr, 1),      Wn = fshl(c, pl, 1);                            \
          u64 NE = fshr(ub.y, u_r, 1),  NW = fshl(ub.y, ub.x, 1);                       \
          u64 SE = fshr(db.y, d_r, 1),  SW = fshl(db.y, db.x, 1);                       \
          rB = zs_word(c, N, NE, E, SE, S, SW, Wn, NW, SUB); }                          \
        ulonglong2 st; st.x = rA; st.y = rB;                                            \
        *reinterpret_cast<ulonglong2*>(&DST[ar][wb]) = st;                              \
        myw0 = rA; myw1 = rB;                                                           \
    }                                                                                   \
    __syncthreads();                                                                    \
} while (0)

// ---------------- kernel 2: closing + 48x thinning in LDS ----------------
__global__ __launch_bounds__(NTHR, 8)
void thin_kernel(const u64* __restrict__ bits, int* __restrict__ out) {
    __shared__ u64 bufA[ARR][PITCH];
    __shared__ u64 bufB[ARR][PITCH];

    const int blk  = blockIdx.x;
    const int z    = blk >> 2;       // slice
    const int band = blk & 3;
    const int r0   = band * BH;      // first output row
    const int la   = (r0 - HALO > 0) ? (r0 - HALO) : 0;
    const int lb   = (r0 + BH + HALO < HH) ? (r0 + BH + HALO) : HH;
    const int nrows = lb - la;       // live rows (<= 232)
    const int ob0  = r0 - la;        // local output start (0 or 52)

    const int t  = threadIdx.x;
    const int lr = t >> 2;           // row handled by this thread (0..255)
    const int q  = t & 3;            // word-pair index 0..3
    const int wb = 2 * q + WOFF;     // LDS idx of first owned word
    const int ar = lr + 2;           // array row (2 guard rows at top)
    const bool act = (lr < nrows);

    u64 myw0 = 0, myw1 = 0;          // register-resident center words

    // ---- zero both buffers (guards/pads must be 0 in both) ----
    {
        u64* fa = &bufA[0][0];
        u64* fb = &bufB[0][0];
        for (int i = t; i < ARR * PITCH; i += NTHR) { fa[i] = 0; fb[i] = 0; }
    }
    __syncthreads();

    // ---- load packed raw mask into bufA live area ----
    if (act) {
        const u64* src = bits + ((long)(z * HH + la + lr)) * WPR + 2 * q;
        ulonglong2 v = *reinterpret_cast<const ulonglong2*>(src);
        *reinterpret_cast<ulonglong2*>(&bufA[ar][wb]) = v;
    }
    __syncthreads();

    // ---- closing: dilation (A->B) then erosion (B->A, seeds registers) ----
    CLOSE_PHASE(bufA, bufB, 1, 0);
    CLOSE_PHASE(bufB, bufA, 0, 1);

    // ---- 48 Zhang-Suen sub-iterations, shrinking active range ----
    #pragma unroll 1
    for (int it2 = 0; it2 < NSUB / 2; ++it2) {
        {
            int hw = NSUB - (2 * it2 + 1);
            int lo = ob0 - hw;       if (lo < 0) lo = 0;
            int hi = ob0 + BH + hw;  if (hi > nrows) hi = nrows;
            THIN_SUB(bufA, bufB, 0, lo, hi);
        }
        {
            int hw = NSUB - (2 * it2 + 2);
            int lo = ob0 - hw;       if (lo < 0) lo = 0;
            int hi = ob0 + BH + hw;  if (hi > nrows) hi = nrows;
            THIN_SUB(bufB, bufA, 1, lo, hi);
        }
    }
    // final state is in bufA

    // ---- expand band rows [r0, r0+BH) to int32 0/1 — R13 coalesced pattern:
    // adjacent lanes write adjacent int4s (dense 1KB/wave segments).
    const long slice_base = (long)z * HH * WWID;
    for (int e = t; e < BH * (WWID / 4); e += NTHR) {
        int rr  = e >> 7;
        int x4  = e & 127;
        int gr  = r0 + rr;
        int arr = (gr - la) + 2;
        int col = x4 * 4;
        u64 w  = bufA[arr][WOFF + (col >> 6)];
        int sh = col & 63;
        int4 f;
        f.x = (int)((w >> (sh + 0)) & 1ull);
        f.y = (int)((w >> (sh + 1)) & 1ull);
        f.z = (int)((w >> (sh + 2)) & 1ull);
        f.w = (int)((w >> (sh + 3)) & 1ull);
        *reinterpret_cast<int4*>(out + slice_base + (long)gr * WWID + col) = f;
    }
}

extern "C" void kernel_launch(void* const* d_in, const int* in_sizes, int n_in,
                              void* d_out, int out_size, void* d_ws, size_t ws_size,
                              hipStream_t stream) {
    const float* in   = (const float*)d_in[0];
    int*         out  = (int*)d_out;
    u64*         bits = (u64*)d_ws;   // 2 MiB scratch

    pack_kernel<<<16384, 256, 0, stream>>>(in, bits);
    thin_kernel<<<DD * BANDS, NTHR, 0, stream>>>(bits, out);
}